// Round 6
// baseline (313.963 us; speedup 1.0000x reference)
//
#include <hip/hip_runtime.h>

typedef __attribute__((ext_vector_type(4))) float floatx4;
typedef __attribute__((ext_vector_type(8))) short short8;
typedef __attribute__((ext_vector_type(4))) unsigned short ushort4v;
typedef __attribute__((ext_vector_type(8))) unsigned short ushort8v;

__device__ __forceinline__ unsigned short f2bf(float f) {
  // round-to-nearest-even fp32 -> bf16 (inputs are finite)
  unsigned int u = __builtin_bit_cast(unsigned int, f);
  u += 0x7FFFu + ((u >> 16) & 1u);
  return (unsigned short)(u >> 16);
}

#define KTOT 784   // true K (28*28)
#define KP   800   // padded K (25 * 32); Bt zeros in [784,800)
#define N1   128   // hidden width
#define BM   32    // rows per block: whole A-slab (32x800 bf16) resident in LDS
#define LDK  804   // LDS k-stride (ushorts): 800 + 4 pad (402 dwords == 18 mod 32)
#define LDH  132   // LDS stride (ushorts) for h / w2t: 128 + 4 pad
#define CK0  104   // chunk0 float4s per row: k in [0,416)   (13 per thread)
#define CK1  96    // chunk1 float4s per row: k in [416,800) (12 per thread)

// lgkmcnt(0)-only barrier: keeps global (vmcnt) loads in flight across the
// workgroup barrier, unlike __syncthreads which drains vmcnt(0).
#define LBAR() do { __builtin_amdgcn_s_waitcnt(0xC07F); __builtin_amdgcn_s_barrier(); } while (0)

// ---------------------------------------------------------------------------
// Prep: W1eff[q][n] = sum_{di,dj} conv_w[di,dj] * w1[(r-di)*26 + (c-dj)][n]
// stored TRANSPOSED as Bt[n][k] bf16, k padded to 800 with zeros.
// ---------------------------------------------------------------------------
__global__ void prep_w1eff(const float* __restrict__ conv_w,
                           const float* __restrict__ w1,
                           unsigned short* __restrict__ Bt) {
  const int n = blockIdx.x;  // 0..127
  float cw[9];
#pragma unroll
  for (int i = 0; i < 9; ++i) cw[i] = conv_w[i];
  for (int q = threadIdx.x; q < KP; q += blockDim.x) {
    float acc = 0.f;
    if (q < KTOT) {
      const int r = q / 28, c = q % 28;
#pragma unroll
      for (int di = 0; di < 3; ++di) {
        const int i2 = r - di;
        if (i2 < 0 || i2 >= 26) continue;
#pragma unroll
        for (int dj = 0; dj < 3; ++dj) {
          const int j2 = c - dj;
          if (j2 < 0 || j2 >= 26) continue;
          acc += cw[di * 3 + dj] * w1[(i2 * 26 + j2) * N1 + n];
        }
      }
    }
    Bt[n * KP + q] = f2bf(acc);
  }
}

// ---------------------------------------------------------------------------
// Fused: out = relu(x @ W1eff + b1) @ w2 + b2
// BM=32, 256 thr (4 waves, each 32 rows x 32 cols), grid 2048, 2 blocks/CU.
// The block's whole A-slab (32 rows x 800 k, bf16, 51.5 KB) is staged into
// LDS in TWO bulk column-chunks with ~1.6-KB contiguous runs per row
// (DRAM page-friendly, vs the 128-B cursor storm of the K-stepped design).
// Chunk1's loads are issued before part-1 compute and land underneath it.
// The K-loop is BARRIER-FREE: A via ds_read from the resident tile, B via
// global->reg from L2-resident Bt (2-step parity prefetch), acc in regs.
// Only 2 barriers per kernel (one per chunk) instead of 25.
// ---------------------------------------------------------------------------
__global__ __launch_bounds__(256, 2)
void fused_mlp(const float* __restrict__ x,
               const unsigned short* __restrict__ Bt,
               const float* __restrict__ b1,
               const float* __restrict__ w2,
               const float* __restrict__ b2,
               float* __restrict__ out) {
  __shared__ __align__(16) unsigned short sAk[BM * LDK];   // 51456 B
  __shared__ __align__(16) unsigned short sH[BM * LDH];    //  8448 B
  __shared__ __align__(16) unsigned short sW2t[16 * LDH];  //  4224 B
  __shared__ float sB1[N1];
  __shared__ float sB2[16];

  const int tid  = threadIdx.x;
  const int wave = tid >> 6;   // 0..3
  const int lane = tid & 63;
  const int wn = wave;         // wave col group: cols [wn*32, wn*32+32)
  const int lr = lane & 15;    // row/col within 16x16 fragment
  const int lq = lane >> 4;    // k-group within fragment

  const long row_base = (long)blockIdx.x * BM;
  const float* xblk = x + row_base * KTOT;

  // ---- chunk0 loads: k in [0,416), all real. 3328 float4s = 13/thread.
  // Consecutive idx -> consecutive addresses: 1664-B contiguous runs/row.
  floatx4 v0[13];
#pragma unroll
  for (int i = 0; i < 13; ++i) {
    const int idx = tid + 256 * i;
    const int r = idx / CK0, ks = idx % CK0;
    v0[i] = *(const floatx4*)(xblk + (long)r * KTOT + ks * 4);
  }

  // preload w2 (transposed bf16, padded to 16 cols), b1, b2
  for (int i = tid; i < 16 * N1; i += 256) {
    const int n = i >> 7, k = i & 127;
    sW2t[n * LDH + k] = (n < 10) ? f2bf(w2[k * 10 + n]) : (unsigned short)0;
  }
  if (tid < N1) sB1[tid] = b1[tid];
  if (tid < 10) sB2[tid] = b2[tid];

  // convert + stage chunk0 (2-way LDS write conflict = free)
#pragma unroll
  for (int i = 0; i < 13; ++i) {
    const int idx = tid + 256 * i;
    const int r = idx / CK0, ks = idx % CK0;
    ushort4v u;
    u[0] = f2bf(v0[i][0]); u[1] = f2bf(v0[i][1]);
    u[2] = f2bf(v0[i][2]); u[3] = f2bf(v0[i][3]);
    *(ushort4v*)&sAk[r * LDK + ks * 4] = u;
  }

  // B fragment machinery: per-lane base into L2-resident Bt
  const unsigned short* btb = Bt + (long)(wn * 32 + lr) * KP + lq * 8;
  ushort8v bb0[2], bb1[2];
  auto loadB = [&](ushort8v* d, int kt) {
    d[0] = *(const ushort8v*)(btb + kt * 32);             // n rows +0..15
    d[1] = *(const ushort8v*)(btb + 16 * KP + kt * 32);   // n rows +16..31
  };
  loadB(bb0, 0);
  loadB(bb1, 1);

  // ---- chunk1 loads: k in [416,800); issued NOW, land under part-1 compute.
  floatx4 v1[12];
#pragma unroll
  for (int i = 0; i < 12; ++i) {
    const int idx = tid + 256 * i;
    const int r = idx / CK1;
    int k = (CK0 + idx % CK1) * 4;
    if (k > KTOT - 4) k = KTOT - 4;  // clamp; garbage killed by Bt zeros
    v1[i] = *(const floatx4*)(xblk + (long)r * KTOT + k);
  }

  LBAR();  // chunk0 staged (lgkm-only: v1 + bb loads stay in flight)

  floatx4 acc[2][2] = {};
  auto mstep = [&](int kt, const ushort8v* b) {
    short8 af[2];
#pragma unroll
    for (int i = 0; i < 2; ++i)
      af[i] = *(const short8*)&sAk[(i * 16 + lr) * LDK + kt * 32 + lq * 8];
#pragma unroll
    for (int im = 0; im < 2; ++im)
#pragma unroll
      for (int in = 0; in < 2; ++in)
        acc[im][in] = __builtin_amdgcn_mfma_f32_16x16x32_bf16(
            af[im], __builtin_bit_cast(short8, b[in]), acc[im][in], 0, 0, 0);
  };

  // ---- part 1: steps 0..12 (k < 416), barrier-free, 2-step B prefetch
#pragma unroll
  for (int kt = 0; kt <= 12; ++kt) {
    mstep(kt, (kt & 1) ? bb1 : bb0);
    if (kt + 2 <= 12) loadB((kt & 1) ? bb1 : bb0, kt + 2);
  }
  // prefetch first part-2 B frags (in flight across the staging + barrier)
  loadB(bb1, 13);
  loadB(bb0, 14);

  // stage chunk1 (vmcnt wait drains v1; bb loads are newer, stay in flight)
#pragma unroll
  for (int i = 0; i < 12; ++i) {
    const int idx = tid + 256 * i;
    const int r = idx / CK1, ks = CK0 + idx % CK1;
    ushort4v u;
    u[0] = f2bf(v1[i][0]); u[1] = f2bf(v1[i][1]);
    u[2] = f2bf(v1[i][2]); u[3] = f2bf(v1[i][3]);
    *(ushort4v*)&sAk[r * LDK + ks * 4] = u;
  }
  LBAR();

  // ---- part 2: steps 13..24
#pragma unroll
  for (int kt = 13; kt <= 24; ++kt) {
    mstep(kt, (kt & 1) ? bb1 : bb0);
    if (kt + 2 <= 24) loadB((kt & 1) ? bb1 : bb0, kt + 2);
  }

  // h = relu(acc + b1) -> bf16 in sH[row][col]
  // C/D layout: col = lane&15, row = (lane>>4)*4 + reg
#pragma unroll
  for (int im = 0; im < 2; ++im) {
#pragma unroll
    for (int in = 0; in < 2; ++in) {
      const int col = wn * 32 + in * 16 + lr;
      const float bbv = sB1[col];
#pragma unroll
      for (int r = 0; r < 4; ++r) {
        const int row = im * 16 + lq * 4 + r;
        const float v = acc[im][in][r] + bbv;
        sH[row * LDH + col] = f2bf(v > 0.f ? v : 0.f);
      }
    }
  }
  __syncthreads();

  // GEMM2: out = h @ w2 + b2. Waves 0,1 handle rows [wave*16, wave*16+16).
  if (wave < 2) {
    floatx4 o0 = {0.f, 0.f, 0.f, 0.f};
    const int m0 = wave * 16;
#pragma unroll
    for (int kc = 0; kc < 4; ++kc) {
      const int kof = kc * 32 + lq * 8;
      const short8 wv = *(const short8*)&sW2t[lr * LDH + kof];
      const short8 a0 = *(const short8*)&sH[(m0 + lr) * LDH + kof];
      o0 = __builtin_amdgcn_mfma_f32_16x16x32_bf16(a0, wv, o0, 0, 0, 0);
    }
    if (lr < 10) {
      const float bbv = sB2[lr];
#pragma unroll
      for (int r = 0; r < 4; ++r) {
        const long row = row_base + m0 + lq * 4 + r;
        out[row * 10 + lr] = o0[r] + bbv;
      }
    }
  }
}

extern "C" void kernel_launch(void* const* d_in, const int* in_sizes, int n_in,
                              void* d_out, int out_size, void* d_ws, size_t ws_size,
                              hipStream_t stream) {
  const float* x      = (const float*)d_in[0];  // 65536 x 784
  const float* conv_w = (const float*)d_in[1];  // 3 x 3
  const float* w1     = (const float*)d_in[2];  // 676 x 128
  const float* b1     = (const float*)d_in[3];  // 128
  const float* w2     = (const float*)d_in[4];  // 128 x 10
  const float* b2     = (const float*)d_in[5];  // 10
  float* out = (float*)d_out;                   // 65536 x 10

  unsigned short* Bt = (unsigned short*)d_ws;   // 128 x 800 bf16 = 204800 B

  prep_w1eff<<<128, 256, 0, stream>>>(conv_w, w1, Bt);
  fused_mlp<<<65536 / BM, 256, 0, stream>>>(x, Bt, b1, w2, b2, out);
}

// Round 7
// 306.119 us; speedup vs baseline: 1.0256x; 1.0256x over previous
//
#include <hip/hip_runtime.h>

typedef __attribute__((ext_vector_type(4))) float floatx4;
typedef __attribute__((ext_vector_type(8))) short short8;
typedef __attribute__((ext_vector_type(4))) unsigned short ushort4v;
typedef __attribute__((ext_vector_type(8))) unsigned short ushort8v;

__device__ __forceinline__ unsigned short f2bf(float f) {
  // round-to-nearest-even fp32 -> bf16 (inputs are finite)
  unsigned int u = __builtin_bit_cast(unsigned int, f);
  u += 0x7FFFu + ((u >> 16) & 1u);
  return (unsigned short)(u >> 16);
}

#define KTOT 784   // true K (28*28)
#define KP   800   // padded K (25 * 32); Bt zeros in [784,800)
#define N1   128   // hidden width
#define BM   128   // rows per block
#define BK   32    // K per MFMA step
#define LDA  36    // LDS stride (ushorts) for A/B tiles: 32 + 4 pad
#define LDH  132   // LDS stride (ushorts) for h / w2t: 128 + 4 pad

// lgkmcnt(0)-only barrier: keeps global (vmcnt) prefetch loads in flight
// across the workgroup barrier, unlike __syncthreads which drains vmcnt(0).
#define LBAR() do { __builtin_amdgcn_s_waitcnt(0xC07F); __builtin_amdgcn_s_barrier(); } while (0)

// ---------------------------------------------------------------------------
// Prep: W1eff[q][n] = sum_{di,dj} conv_w[di,dj] * w1[(r-di)*26 + (c-dj)][n]
// stored TRANSPOSED as Bt[n][k] bf16, k padded to 800 with zeros.
// ---------------------------------------------------------------------------
__global__ void prep_w1eff(const float* __restrict__ conv_w,
                           const float* __restrict__ w1,
                           unsigned short* __restrict__ Bt) {
  const int n = blockIdx.x;  // 0..127
  float cw[9];
#pragma unroll
  for (int i = 0; i < 9; ++i) cw[i] = conv_w[i];
  for (int q = threadIdx.x; q < KP; q += blockDim.x) {
    float acc = 0.f;
    if (q < KTOT) {
      const int r = q / 28, c = q % 28;
#pragma unroll
      for (int di = 0; di < 3; ++di) {
        const int i2 = r - di;
        if (i2 < 0 || i2 >= 26) continue;
#pragma unroll
        for (int dj = 0; dj < 3; ++dj) {
          const int j2 = c - dj;
          if (j2 < 0 || j2 >= 26) continue;
          acc += cw[di * 3 + dj] * w1[(i2 * 26 + j2) * N1 + n];
        }
      }
    }
    Bt[n * KP + q] = f2bf(acc);
  }
}

// ---------------------------------------------------------------------------
// Fused: out = relu(x @ W1eff + b1) @ w2 + b2
// 256 thr (2x2 waves), BM=128, K-loop 25 x BK=32, DEPTH-2 register-prefetch
// (3-way reg rotation over 2 LDS buffers), ONE lgkm-only barrier per K-step.
// Best-measured configuration of the session (306.4 us); seven structural
// variants (occupancy up/down, no-LDS, BK=64, barrier-domain split,
// bulk-chunk streaming) all measured neutral-to-worse.
// ---------------------------------------------------------------------------
__global__ __launch_bounds__(256, 2)
void fused_mlp(const float* __restrict__ x,
               const unsigned short* __restrict__ Bt,
               const float* __restrict__ b1,
               const float* __restrict__ w2,
               const float* __restrict__ b2,
               float* __restrict__ out) {
  __shared__ __align__(16) unsigned short sA[2 * BM * LDA];   // 18432 B
  __shared__ __align__(16) unsigned short sB[2 * N1 * LDA];   // 18432 B
  __shared__ __align__(16) unsigned short sH[BM * LDH];       // 33792 B
  __shared__ __align__(16) unsigned short sW2t[16 * LDH];     //  4224 B
  __shared__ float sB1[N1];
  __shared__ float sB2[16];

  const int tid  = threadIdx.x;
  const int wave = tid >> 6;
  const int lane = tid & 63;
  const int wm = wave & 1;   // wave row (2x2 wave grid)
  const int wn = wave >> 1;  // wave col
  const int lr = lane & 15;  // row/col within 16x16 fragment
  const int lq = lane >> 4;  // quad index (k-group / acc row group)

  const long row_base = (long)blockIdx.x * BM;
  const float* xblk = x + row_base * KTOT;

  // preload w2 (transposed, bf16, padded to 16 cols), b1, b2
  for (int i = tid; i < 16 * N1; i += 256) {
    const int n = i >> 7, k = i & 127;
    sW2t[n * LDH + k] = (n < 10) ? f2bf(w2[k * 10 + n]) : (unsigned short)0;
  }
  if (tid < N1) sB1[tid] = b1[tid];
  if (tid < 10) sB2[tid] = b2[tid];

  // staging thread mapping
  const int akp = tid & 7;   // which float4 of the 32-float row chunk
  const int arp = tid >> 3;  // row within a 32-row pass (4 passes)
  const int bkp = tid & 3;   // which ushort8 of the 32-bf16 row chunk
  const int bnp = tid >> 2;  // n within a 64-row pass (2 passes)

  floatx4 acc[4][4] = {};

  auto load_a = [&](floatx4* pa, int kt) {
    const int k0 = kt * BK;
#pragma unroll
    for (int p = 0; p < 4; ++p) {
      const int row = p * 32 + arp;
      int kk = k0 + akp * 4;
      if (kk >= KTOT) kk = KTOT - 16;  // clamp; k>=784 values killed by Bt zeros
      pa[p] = *(const floatx4*)(xblk + (long)row * KTOT + kk);
    }
  };
  auto load_b = [&](ushort8v* pb, int kt) {
    const int k0 = kt * BK;
#pragma unroll
    for (int p = 0; p < 2; ++p) {
      const int n = p * 64 + bnp;
      pb[p] = *(const ushort8v*)(Bt + n * KP + k0 + bkp * 8);
    }
  };
  auto store_tile = [&](int buf, const floatx4* pa, const ushort8v* pb) {
    unsigned short* A  = sA + buf * (BM * LDA);
    unsigned short* Bs = sB + buf * (N1 * LDA);
#pragma unroll
    for (int p = 0; p < 4; ++p) {
      ushort4v u;
      u[0] = f2bf(pa[p][0]); u[1] = f2bf(pa[p][1]);
      u[2] = f2bf(pa[p][2]); u[3] = f2bf(pa[p][3]);
      *(ushort4v*)&A[(p * 32 + arp) * LDA + akp * 4] = u;
    }
#pragma unroll
    for (int p = 0; p < 2; ++p)
      *(ushort8v*)&Bs[(p * 64 + bnp) * LDA + bkp * 8] = pb[p];
  };
  auto mfma_step = [&](int buf) {
    const unsigned short* A  = sA + buf * (BM * LDA);
    const unsigned short* Bs = sB + buf * (N1 * LDA);
    short8 af[4], bfv[4];
#pragma unroll
    for (int i = 0; i < 4; ++i)
      af[i] = *(const short8*)&A[(wm * 64 + i * 16 + lr) * LDA + lq * 8];
#pragma unroll
    for (int i = 0; i < 4; ++i)
      bfv[i] = *(const short8*)&Bs[(wn * 64 + i * 16 + lr) * LDA + lq * 8];
#pragma unroll
    for (int im = 0; im < 4; ++im)
#pragma unroll
      for (int in = 0; in < 4; ++in)
        acc[im][in] = __builtin_amdgcn_mfma_f32_16x16x32_bf16(
            af[im], bfv[in], acc[im][in], 0, 0, 0);
  };

  // K-loop: 25 steps, DEPTH-2 prefetch. Registers rotate mod 3 (all indices
  // compile-time via the fully-unrolled 6-step body); LDS buffers alternate.
  // At each store_tile's implicit vmcnt-wait, the 2 newer steps' loads
  // remain in flight.
  floatx4 pA[3][4];
  ushort8v pB[3][2];
  load_a(pA[0], 0); load_b(pB[0], 0);
  load_a(pA[1], 1); load_b(pB[1], 1);
#pragma unroll 1
  for (int base = 0; base < 24; base += 6) {
#pragma unroll
    for (int s = 0; s < 6; ++s) {
      const int kt = base + s;          // kt%3 == s%3 (base%6==0), kt&1 == s&1
      if (kt + 2 <= 24) {               // compile-time folded per instance
        load_a(pA[(s + 2) % 3], kt + 2);
        load_b(pB[(s + 2) % 3], kt + 2);
      }
      store_tile(s & 1, pA[s % 3], pB[s % 3]);
      LBAR();
      mfma_step(s & 1);
    }
  }
  store_tile(0, pA[0], pB[0]);          // kt = 24 (24%3==0, buf 0)
  LBAR();
  mfma_step(0);

  // h = relu(acc + b1) -> bf16 in sH[row][col]
  // C/D layout: col = lane&15, row = (lane>>4)*4 + reg
#pragma unroll
  for (int im = 0; im < 4; ++im) {
#pragma unroll
    for (int in = 0; in < 4; ++in) {
      const int col = wn * 64 + in * 16 + lr;
      const float bb = sB1[col];
#pragma unroll
      for (int r = 0; r < 4; ++r) {
        const int row = wm * 64 + im * 16 + lq * 4 + r;
        const float v = acc[im][in][r] + bb;
        sH[row * LDH + col] = f2bf(v > 0.f ? v : 0.f);
      }
    }
  }
  __syncthreads();  // full drain is fine once, at the epilogue

  // GEMM2: out = h @ w2 + b2. Wave handles rows [wave*32, wave*32+32).
  floatx4 o0 = {0.f, 0.f, 0.f, 0.f}, o1 = {0.f, 0.f, 0.f, 0.f};
  const int m0 = wave * 32;
#pragma unroll
  for (int kc = 0; kc < 4; ++kc) {
    const int kof = kc * 32 + lq * 8;
    const short8 wv = *(const short8*)&sW2t[lr * LDH + kof];
    const short8 a0 = *(const short8*)&sH[(m0 + lr) * LDH + kof];
    const short8 a1 = *(const short8*)&sH[(m0 + 16 + lr) * LDH + kof];
    o0 = __builtin_amdgcn_mfma_f32_16x16x32_bf16(a0, wv, o0, 0, 0, 0);
    o1 = __builtin_amdgcn_mfma_f32_16x16x32_bf16(a1, wv, o1, 0, 0, 0);
  }
  if (lr < 10) {
    const float bb = sB2[lr];
#pragma unroll
    for (int r = 0; r < 4; ++r) {
      const long row = row_base + m0 + lq * 4 + r;
      out[row * 10 + lr] = o0[r] + bb;
      out[(row + 16) * 10 + lr] = o1[r] + bb;
    }
  }
}

extern "C" void kernel_launch(void* const* d_in, const int* in_sizes, int n_in,
                              void* d_out, int out_size, void* d_ws, size_t ws_size,
                              hipStream_t stream) {
  const float* x      = (const float*)d_in[0];  // 65536 x 784
  const float* conv_w = (const float*)d_in[1];  // 3 x 3
  const float* w1     = (const float*)d_in[2];  // 676 x 128
  const float* b1     = (const float*)d_in[3];  // 128
  const float* w2     = (const float*)d_in[4];  // 128 x 10
  const float* b2     = (const float*)d_in[5];  // 10
  float* out = (float*)d_out;                   // 65536 x 10

  unsigned short* Bt = (unsigned short*)d_ws;   // 128 x 800 bf16 = 204800 B

  prep_w1eff<<<128, 256, 0, stream>>>(conv_w, w1, Bt);
  fused_mlp<<<65536 / BM, 256, 0, stream>>>(x, Bt, b1, w2, b2, out);
}